// Round 11
// baseline (103.821 us; speedup 1.0000x reference)
//
#include <hip/hip_runtime.h>
#include <hip/hip_fp16.h>
#include <math.h>

#define N_NODES 2000
#define N_EDGES 32000
#define BB 16
#define TT 20
#define NG (BB*TT)      // 320 graphs
#define OUTF 8
#define HID 24
#define FC_OUTD 160
#define FCC_OUTD 20
#define PWAVES 512      // node-range partitions (waves per graph-group)

// ---- workspace offsets (bytes), new path ----
#define WS_ROWPTR  0          // int[2001]
#define WS_WAVEN0  8192       // int[513]
#define WS_CURSOR  16384      // int[2000]
#define WS_META    24576      // u32[32000] CSR-ordered: src|dst<<11|flag<<22
#define WS_POS     155648     // u32[32000] e -> csr pos
#define WS_FEATS   286720     // float[2560]
#define WS_M       296960     // float[480]
#define WS_B2      298880     // float[20]
#define WS_PART    303104     // float[512*320*2]
#define WS_XT      1617920    // half[2000*320]
#define WS_EW2     2899968    // half[rows*320]
#define REQ1 23379968ull      // rows = 32000 (single pass)
#define REQ2 13385728ull      // rows = 16384 (two passes)

// ================= builders =================

__global__ __launch_bounds__(1024) void build1(const int* __restrict__ dst,
    int* __restrict__ row_ptr, int* __restrict__ waveN0, int* __restrict__ cursor)
{
    __shared__ int a[2048], b[2048];
    const int tid = threadIdx.x;
    a[tid] = 0; a[tid + 1024] = 0;
    __syncthreads();
    for (int e = tid; e < N_EDGES; e += 1024) atomicAdd(&a[dst[e]], 1);
    __syncthreads();
    int *s = a, *d = b;
    for (int off = 1; off < 2048; off <<= 1) {
        d[tid] = s[tid] + (tid >= off ? s[tid - off] : 0);
        const int j = tid + 1024;
        d[j] = s[j] + (j >= off ? s[j - off] : 0);
        __syncthreads();
        int* t = s; s = d; d = t;
    }
    if (tid == 0) row_ptr[0] = 0;
    for (int i = tid; i < N_NODES; i += 1024) { row_ptr[i + 1] = s[i]; cursor[i] = 0; }
    // wave partition: waveN0[w] = first node n with inclusive[n] > w*62.5
    if (tid <= PWAVES) {
        if (tid == PWAVES) waveN0[tid] = N_NODES;
        else {
            const int target = (int)(((long long)tid * N_EDGES) >> 9);
            int lo = 0, hi = N_NODES;
            while (lo < hi) { int mid = (lo + hi) >> 1; if (s[mid] <= target) lo = mid + 1; else hi = mid; }
            waveN0[tid] = lo;
        }
    }
}

__global__ __launch_bounds__(1024) void build2(
    const int* __restrict__ src, const int* __restrict__ dst,
    const int* __restrict__ row_ptr, int* __restrict__ cursor,
    unsigned* __restrict__ meta, unsigned* __restrict__ pos,
    const float* __restrict__ fc_w, const float* __restrict__ fc_b,
    const float* __restrict__ fcc_w, const float* __restrict__ fcc_b,
    float* __restrict__ Mout, float* __restrict__ b2out)
{
    const int tid = threadIdx.x;
    if (blockIdx.x == 32) {    // fused projection M = fcc_w @ fc_w ; b2 = fcc_b + fcc_w @ fc_b
        if (tid < FCC_OUTD * HID) {
            const int j = tid / HID, hh = tid % HID;
            float acc = 0.f;
#pragma unroll 4
            for (int m = 0; m < FC_OUTD; ++m)
                acc += fcc_w[j * FC_OUTD + m] * fc_w[m * HID + hh];
            Mout[tid] = acc;
        } else if (tid < FCC_OUTD * HID + FCC_OUTD) {
            const int j = tid - FCC_OUTD * HID;
            float acc = fcc_b[j];
#pragma unroll 4
            for (int m = 0; m < FC_OUTD; ++m)
                acc += fcc_w[j * FC_OUTD + m] * fc_b[m];
            b2out[j] = acc;
        }
        return;
    }
    const int e = blockIdx.x * 1024 + tid;
    if (e >= N_EDGES) return;
    const int s = src[e], d = dst[e];
    const int rp = row_ptr[d];
    const int p  = rp + atomicAdd(&cursor[d], 1);
    const unsigned fl = (p == rp) ? 1u : 0u;
    meta[p] = (unsigned)s | ((unsigned)d << 11) | (fl << 22);
    pos[e]  = (unsigned)p;
}

// ===== transpose: edge_w[g][e] -> ew2[pos][g] fp16 ; x[g][n] -> xT[n][g] fp16 =====

__global__ __launch_bounds__(256) void trans_kernel(
    const float* __restrict__ edge_w, const float* __restrict__ x,
    const unsigned* __restrict__ pos,
    const int* __restrict__ row_ptr, const int* __restrict__ waveN0,
    __half* __restrict__ ew2, __half* __restrict__ xT, int h, int nh)
{
    __shared__ __half lw[64 * 65];
    __shared__ unsigned ps[64];
    const int tid = threadIdx.x, bi = blockIdx.x;
    const int r16 = tid >> 4, c4 = tid & 15;
    const int wv = tid >> 6, lane = tid & 63;

    if (bi < 2500) {           // edge_w tiles: 500 e-tiles x 5 g-tiles
        int Elo = 0, Ehi = N_EDGES;
        if (nh == 2) {
            const int mid = row_ptr[waveN0[PWAVES / 2]];
            if (h == 0) Ehi = mid; else Elo = mid;
        }
        const int et = bi % 500, gt = bi / 500;
        const int e0 = et * 64, g0 = gt * 64;
        const float4* in4 = (const float4*)edge_w;
#pragma unroll
        for (int rr = 0; rr < 4; ++rr) {
            const int grow = rr * 16 + r16;
            const float4 v = in4[(size_t)(g0 + grow) * (N_EDGES / 4) + (e0 >> 2) + c4];
            const int eb = c4 * 4;
            lw[(eb + 0) * 65 + grow] = __float2half(v.x);
            lw[(eb + 1) * 65 + grow] = __float2half(v.y);
            lw[(eb + 2) * 65 + grow] = __float2half(v.z);
            lw[(eb + 3) * 65 + grow] = __float2half(v.w);
        }
        if (tid < 64) ps[tid] = pos[e0 + tid];
        __syncthreads();
#pragma unroll
        for (int q = 0; q < 16; ++q) {
            const int e = wv * 16 + q;
            const int p = (int)ps[e];
            if (p >= Elo && p < Ehi)
                ew2[(size_t)(p - Elo) * 320 + g0 + lane] = lw[e * 65 + lane];
        }
    } else {                   // x tiles: 32 n-tiles x 5 g-tiles (only on pass 0)
        if (h != 0) return;
        const int i = bi - 2500;
        const int nt = i % 32, gt = i / 32;
        const int n0 = nt * 64, g0 = gt * 64;
        const float4* in4 = (const float4*)x;
#pragma unroll
        for (int rr = 0; rr < 4; ++rr) {
            const int grow = rr * 16 + r16;
            const int col4 = (n0 >> 2) + c4;
            if (col4 < N_NODES / 4) {
                const float4 v = in4[(size_t)(g0 + grow) * (N_NODES / 4) + col4];
                const int eb = c4 * 4;
                lw[(eb + 0) * 65 + grow] = __float2half(v.x);
                lw[(eb + 1) * 65 + grow] = __float2half(v.y);
                lw[(eb + 2) * 65 + grow] = __float2half(v.z);
                lw[(eb + 3) * 65 + grow] = __float2half(v.w);
            }
        }
        __syncthreads();
#pragma unroll
        for (int q = 0; q < 16; ++q) {
            const int n = wv * 16 + q;
            if (n0 + n < N_NODES)
                xT[(size_t)(n0 + n) * 320 + g0 + lane] = lw[n * 65 + lane];
        }
    }
}

// ===== GAT main: lane=graph, wave=CSR node-range; register segmented reduction =====

__global__ __launch_bounds__(256) void gat_main(
    const __half* __restrict__ ew2, const __half* __restrict__ xT,
    const unsigned* __restrict__ meta, const int* __restrict__ row_ptr,
    const int* __restrict__ waveN0,
    const float* __restrict__ W_node, const float* __restrict__ W_edge,
    const float* __restrict__ attn_l, const float* __restrict__ attn_e,
    const float* __restrict__ attn_r,
    float* __restrict__ part, int h, int nrb)
{
    __shared__ unsigned smeta[512];
    const int tid  = threadIdx.x;
    const int nr   = h * nrb + (blockIdx.x % nrb);
    const int grp  = blockIdx.x / nrb;
    const int w    = tid >> 6, lane = tid & 63;
    const int wid  = nr * 4 + w;

    float cl = 0.f, ce = 0.f, cr = 0.f;
#pragma unroll
    for (int k = 0; k < OUTF; ++k) {
        cl += W_node[k] * attn_l[k];
        cr += W_node[k] * attn_r[k];
        ce += W_edge[k] * attn_e[k];
    }

    const int Elo = (h == 0) ? 0 : row_ptr[waveN0[PWAVES / 2]];
    const int P0 = row_ptr[waveN0[nr * 4]];
    const int P1 = row_ptr[waveN0[nr * 4 + 4]];
    const int cnt = P1 - P0;
    for (int i = tid; i < cnt && i < 512; i += 256) smeta[i] = meta[P0 + i];
    __syncthreads();

    const int p0 = row_ptr[waveN0[wid]];
    const int p1 = row_ptr[waveN0[wid + 1]];

    const __half* ewp = ew2 + grp * 64 + lane;
    const __half* xtp = xT  + grp * 64 + lane;

    float s1 = 0.f, s2 = 0.f, den = 0.f, t1 = 0.f, t2 = 0.f, xd = 0.f;
    int started = 0;
    unsigned pm[4]; float pw[4], pxs[4], pxd[4];
    const int n = p1 - p0;

#pragma unroll
    for (int k = 0; k < 4; ++k) {
        if (k < n) {
            const unsigned m = smeta[p0 - P0 + k];
            pm[k] = m;
            pw[k]  = __half2float(ewp[(size_t)(p0 + k - Elo) * 320]);
            pxs[k] = __half2float(xtp[(size_t)(m & 2047u) * 320]);
            pxd[k] = __half2float(xtp[(size_t)((m >> 11) & 2047u) * 320]);
        } else { pm[k] = 0; pw[k] = 0.f; pxs[k] = 0.f; pxd[k] = 0.f; }
    }
    int pc = p0 + 4;

#define STEP(r) { \
    const unsigned m = pm[r]; const float wv = pw[r], xsv = pxs[r], xdv = pxd[r]; \
    if (pc < p1) { const unsigned m2 = smeta[pc - P0]; pm[r] = m2; \
        pw[r]  = __half2float(ewp[(size_t)(pc - Elo) * 320]); \
        pxs[r] = __half2float(xtp[(size_t)(m2 & 2047u) * 320]); \
        pxd[r] = __half2float(xtp[(size_t)((m2 >> 11) & 2047u) * 320]); ++pc; } \
    if (m & (1u << 22)) { if (started) { s1 += t1 / den; s2 += t2 / den; } \
        started = 1; den = 0.f; t1 = 0.f; t2 = 0.f; xd = xdv; } \
    float ev = cl * xsv + ce * wv + cr * xd; \
    ev = fmaxf(ev, 0.2f * ev); \
    const float num = __expf(ev); \
    den += num; t1 = fmaf(num, xsv, t1); t2 = fmaf(num, wv, t2); }

    const int nb = n >> 2;
    for (int b = 0; b < nb; ++b) { STEP(0) STEP(1) STEP(2) STEP(3) }
    const int rem = n & 3;
    if (rem > 0) STEP(0)
    if (rem > 1) STEP(1)
    if (rem > 2) STEP(2)
#undef STEP
    if (started) { s1 += t1 / den; s2 += t2 / den; }

    const int g = grp * 64 + lane;
    part[((size_t)wid * 320 + g) * 2 + 0] = s1;
    part[((size_t)wid * 320 + g) * 2 + 1] = s2;
}

// ===== reduce partials -> feats =====

__global__ __launch_bounds__(256) void reduce_kernel(const float* __restrict__ part,
    const float* __restrict__ W_node, const float* __restrict__ W_edge,
    const float* __restrict__ gat_b, float* __restrict__ feats)
{
    __shared__ double ra[4], rc[4];
    const int g = blockIdx.x, tid = threadIdx.x;
    double a = 0.0, c = 0.0;
    for (int wid = tid; wid < PWAVES; wid += 256) {
        a += part[((size_t)wid * 320 + g) * 2 + 0];
        c += part[((size_t)wid * 320 + g) * 2 + 1];
    }
#pragma unroll
    for (int off = 32; off > 0; off >>= 1) { a += __shfl_down(a, off, 64); c += __shfl_down(c, off, 64); }
    if ((tid & 63) == 0) { ra[tid >> 6] = a; rc[tid >> 6] = c; }
    __syncthreads();
    if (tid == 0) {
        a = ra[0] + ra[1] + ra[2] + ra[3];
        c = rc[0] + rc[1] + rc[2] + rc[3];
#pragma unroll
        for (int k = 0; k < OUTF; ++k)
            feats[g * OUTF + k] = gat_b[k] +
                (float)((a * (double)W_node[k] + c * (double)W_edge[k]) / (double)N_NODES);
    }
}

// ===== fallback (proven round-6 path): int-fixed-point LDS atomics =====

#define SC_DEN 4194304.0f
#define SC_T1  524288.0f
#define SC_T2  4194304.0f
#define XBIAS  8.0f

__global__ __launch_bounds__(1024) void gat_fb(
    const float* __restrict__ x, const float* __restrict__ edge_w,
    const int* __restrict__ src, const int* __restrict__ dst,
    const float* __restrict__ W_node, const float* __restrict__ W_edge,
    const float* __restrict__ attn_l, const float* __restrict__ attn_e,
    const float* __restrict__ attn_r, const float* __restrict__ gat_b,
    const float* __restrict__ fc_w, const float* __restrict__ fc_b,
    const float* __restrict__ fcc_w, const float* __restrict__ fcc_b,
    float* __restrict__ ws)
{
    __shared__ float              xs[N_NODES];
    __shared__ unsigned           aden[N_NODES];
    __shared__ unsigned long long apk[N_NODES];
    __shared__ double wr1[16], wr2[16];
    const int tid = threadIdx.x;
    if (blockIdx.x == NG) {
        if (tid < FCC_OUTD * HID) {
            const int j = tid / HID, hh = tid % HID;
            float acc = 0.f;
#pragma unroll 4
            for (int m = 0; m < FC_OUTD; ++m) acc += fcc_w[j * FC_OUTD + m] * fc_w[m * HID + hh];
            ws[NG * OUTF + tid] = acc;
        } else if (tid < FCC_OUTD * HID + FCC_OUTD) {
            const int j = tid - FCC_OUTD * HID;
            float acc = fcc_b[j];
#pragma unroll 4
            for (int m = 0; m < FC_OUTD; ++m) acc += fcc_w[j * FC_OUTD + m] * fc_b[m];
            ws[NG * OUTF + FCC_OUTD * HID + j] = acc;
        }
        return;
    }
    const int g = blockIdx.x;
    float cl = 0.f, ce = 0.f, cr = 0.f;
#pragma unroll
    for (int k = 0; k < OUTF; ++k) {
        cl += W_node[k] * attn_l[k];
        cr += W_node[k] * attn_r[k];
        ce += W_edge[k] * attn_e[k];
    }
    const float* xg = x + (size_t)g * N_NODES;
    const float* wg = edge_w + (size_t)g * N_EDGES;
    {
        const float4* xg4 = (const float4*)xg;
        for (int i = tid; i < N_NODES / 4; i += 1024) ((float4*)xs)[i] = xg4[i];
        for (int i = tid; i < N_NODES; i += 1024) { aden[i] = 0u; apk[i] = 0ull; }
    }
    __syncthreads();
    const int4*   src4 = (const int4*)src;
    const int4*   dst4 = (const int4*)dst;
    const float4* wg4  = (const float4*)wg;
#pragma unroll
    for (int k = 0; k < (N_EDGES / 4 + 1023) / 1024; ++k) {
        const int c = tid + k * 1024;
        if (c < N_EDGES / 4) {
            const int4 sv = src4[c]; const int4 dv = dst4[c]; const float4 wv = wg4[c];
#pragma unroll
            for (int j = 0; j < 4; ++j) {
                const int s = (&sv.x)[j], d = (&dv.x)[j];
                const float w = (&wv.x)[j];
                const float xsv = xs[s];
                float ev = cl * xsv + ce * w + cr * xs[d];
                ev = fmaxf(ev, 0.2f * ev);
                const float num = __expf(ev);
                const unsigned deni = __float2uint_rn(num * SC_DEN);
                const unsigned t1i  = __float2uint_rn(num * (xsv + XBIAS) * SC_T1);
                const unsigned t2i  = __float2uint_rn(num * w * SC_T2);
                atomicAdd(&aden[d], deni);
                atomicAdd(&apk[d], ((unsigned long long)t2i << 32) | (unsigned long long)t1i);
            }
        }
    }
    __syncthreads();
    double s1 = 0.0, s2 = 0.0;
    for (int nn = tid; nn < N_NODES; nn += 1024) {
        const unsigned deni = aden[nn];
        if (deni) {
            const unsigned long long pk = apk[nn];
            const double inv = 1.0 / (double)deni;
            s1 += 8.0 * (double)(unsigned)(pk & 0xffffffffull) * inv - 8.0;
            s2 += (double)(unsigned)(pk >> 32) * inv;
        }
    }
#pragma unroll
    for (int off = 32; off > 0; off >>= 1) { s1 += __shfl_down(s1, off, 64); s2 += __shfl_down(s2, off, 64); }
    const int wave = tid >> 6, lane = tid & 63;
    if (lane == 0) { wr1[wave] = s1; wr2[wave] = s2; }
    __syncthreads();
    if (tid == 0) {
        double a = 0.0, c = 0.0;
#pragma unroll
        for (int wv2 = 0; wv2 < 16; ++wv2) { a += wr1[wv2]; c += wr2[wv2]; }
#pragma unroll
        for (int k = 0; k < OUTF; ++k)
            ws[g * OUTF + k] = gat_b[k] +
                (float)((a * (double)W_node[k] + c * (double)W_edge[k]) / (double)N_NODES);
    }
}

// ===== head: LSTM + fused projection (shared by both paths) =====

__device__ __forceinline__ float fast_sigmoid(float v) { return 1.f / (1.f + __expf(-v)); }
__device__ __forceinline__ float fast_tanh(float v) {
    const float t = __expf(2.f * v);
    return (t - 1.f) / (t + 1.f);
}

__global__ __launch_bounds__(128) void lstm_head(
    const float* __restrict__ feats, const float* __restrict__ Mw,
    const float* __restrict__ b2w,
    const float* __restrict__ w_ih, const float* __restrict__ w_hh,
    const float* __restrict__ b_ih, const float* __restrict__ b_hh,
    float* __restrict__ out)
{
    __shared__ float s_M[FCC_OUTD * HID];
    __shared__ float s_b2[FCC_OUTD];
    __shared__ float s_xt[TT * OUTF];
    __shared__ float s_bias[96];
    __shared__ float s_xg[TT * 96];
    __shared__ float s_g[96];
    __shared__ float s_h[HID], s_c[HID];
    __shared__ float s_hs[TT * HID];

    const int b = blockIdx.x, tid = threadIdx.x;
    for (int i = tid; i < FCC_OUTD * HID; i += 128) s_M[i] = Mw[i];
    if (tid < FCC_OUTD) s_b2[tid] = b2w[tid];
    for (int i = tid; i < TT * OUTF; i += 128) s_xt[i] = feats[b * TT * OUTF + i];
    if (tid < 96) s_bias[tid] = b_ih[tid] + b_hh[tid];
    if (tid < HID) { s_h[tid] = 0.f; s_c[tid] = 0.f; }
    float rw_hh[HID];
    if (tid < 96) {
#pragma unroll
        for (int k = 0; k < HID; ++k) rw_hh[k] = w_hh[tid * HID + k];
    }
    __syncthreads();
    for (int u = tid; u < TT * 96; u += 128) {
        const int t = u / 96, j = u % 96;
        float acc = s_bias[j];
        const float* xt = &s_xt[t * OUTF];
#pragma unroll
        for (int k = 0; k < OUTF; ++k) acc += xt[k] * w_ih[j * OUTF + k];
        s_xg[u] = acc;
    }
    __syncthreads();
    for (int t = 0; t < TT; ++t) {
        if (tid < 96) {
            float acc = s_xg[t * 96 + tid];
#pragma unroll
            for (int k = 0; k < HID; ++k) acc += s_h[k] * rw_hh[k];
            s_g[tid] = acc;
        }
        __syncthreads();
        if (tid < HID) {
            const float i_ = fast_sigmoid(s_g[tid]);
            const float f_ = fast_sigmoid(s_g[24 + tid]);
            const float g_ = fast_tanh(s_g[48 + tid]);
            const float o_ = fast_sigmoid(s_g[72 + tid]);
            const float c = f_ * s_c[tid] + i_ * g_;
            s_c[tid] = c;
            const float hv = o_ * fast_tanh(c);
            s_h[tid] = hv;
            s_hs[t * HID + tid] = hv;
        }
        __syncthreads();
    }
    for (int u = tid; u < TT * FCC_OUTD; u += 128) {
        const int t = u / FCC_OUTD, j = u % FCC_OUTD;
        float acc = s_b2[j];
        const float* hr = &s_hs[t * HID];
#pragma unroll
        for (int hh = 0; hh < HID; ++hh) acc += hr[hh] * s_M[j * HID + hh];
        out[(b * TT + t) * FCC_OUTD + j] = acc;
    }
}

extern "C" void kernel_launch(void* const* d_in, const int* in_sizes, int n_in,
                              void* d_out, int out_size, void* d_ws, size_t ws_size,
                              hipStream_t stream) {
    const float* x      = (const float*)d_in[0];
    const float* edge_w = (const float*)d_in[1];
    const int*   src    = (const int*)d_in[2];
    const int*   dst    = (const int*)d_in[3];
    const float* W_node = (const float*)d_in[4];
    const float* W_edge = (const float*)d_in[5];
    const float* attn_l = (const float*)d_in[6];
    const float* attn_e = (const float*)d_in[7];
    const float* attn_r = (const float*)d_in[8];
    const float* gat_b  = (const float*)d_in[9];
    const float* w_ih   = (const float*)d_in[10];
    const float* w_hh   = (const float*)d_in[11];
    const float* b_ih   = (const float*)d_in[12];
    const float* b_hh   = (const float*)d_in[13];
    const float* fc_w   = (const float*)d_in[14];
    const float* fc_b   = (const float*)d_in[15];
    const float* fcc_w  = (const float*)d_in[16];
    const float* fcc_b  = (const float*)d_in[17];
    float* out = (float*)d_out;
    char*  ws  = (char*)d_ws;

    if (ws_size >= REQ2) {
        int*      row_ptr = (int*)(ws + WS_ROWPTR);
        int*      waveN0  = (int*)(ws + WS_WAVEN0);
        int*      cursor  = (int*)(ws + WS_CURSOR);
        unsigned* meta    = (unsigned*)(ws + WS_META);
        unsigned* pos     = (unsigned*)(ws + WS_POS);
        float*    feats   = (float*)(ws + WS_FEATS);
        float*    Mw      = (float*)(ws + WS_M);
        float*    b2w     = (float*)(ws + WS_B2);
        float*    part    = (float*)(ws + WS_PART);
        __half*   xT      = (__half*)(ws + WS_XT);
        __half*   ew2     = (__half*)(ws + WS_EW2);
        const int nh  = (ws_size >= REQ1) ? 1 : 2;
        const int nrb = 128 / nh;    // nr-blocks per pass (x5 graph groups)

        build1<<<1, 1024, 0, stream>>>(dst, row_ptr, waveN0, cursor);
        build2<<<33, 1024, 0, stream>>>(src, dst, row_ptr, cursor, meta, pos,
                                        fc_w, fc_b, fcc_w, fcc_b, Mw, b2w);
        for (int h = 0; h < nh; ++h) {
            trans_kernel<<<2660, 256, 0, stream>>>(edge_w, x, pos, row_ptr, waveN0,
                                                   ew2, xT, h, nh);
            gat_main<<<nrb * 5, 256, 0, stream>>>(ew2, xT, meta, row_ptr, waveN0,
                                                  W_node, W_edge, attn_l, attn_e, attn_r,
                                                  part, h, nrb);
        }
        reduce_kernel<<<NG, 256, 0, stream>>>(part, W_node, W_edge, gat_b, feats);
        lstm_head<<<BB, 128, 0, stream>>>(feats, Mw, b2w, w_ih, w_hh, b_ih, b_hh, out);
    } else {
        // fallback: proven round-6 path (ws floats: feats@0, M@2560, b2@3040)
        float* wsf = (float*)ws;
        gat_fb<<<NG + 1, 1024, 0, stream>>>(x, edge_w, src, dst, W_node, W_edge,
                                            attn_l, attn_e, attn_r, gat_b,
                                            fc_w, fc_b, fcc_w, fcc_b, wsf);
        lstm_head<<<BB, 128, 0, stream>>>(wsf, wsf + 2560, wsf + 3040,
                                          w_ih, w_hh, b_ih, b_hh, out);
    }
}

// Round 12
// 56.562 us; speedup vs baseline: 1.8355x; 1.8355x over previous
//
#include <hip/hip_runtime.h>
#include <math.h>

#define N_NODES 2000
#define N_EDGES 32000
#define BB 16
#define TT 20
#define NG (BB*TT)      // 320 graphs
#define OUTF 8
#define HID 24
#define FC_OUTD 160
#define FCC_OUTD 20
#define NSLICE 2
#define ESL (N_EDGES/NSLICE)     // 16000 edges per slice
#define EV4 (ESL/4)              // 4000 vec4 groups per slice

// fixed-point scales (native ds_add_u32/u64, no CAS, bit-deterministic; proven round 4-6)
#define SC_DEN 4194304.0f    // 2^22 : den = sum(num)
#define SC_T1  524288.0f     // 2^19 : t1' = sum(num*(x+8)) >= 0 (lo32)
#define SC_T2  4194304.0f    // 2^22 : t2  = sum(num*w) (hi32)
#define XBIAS  8.0f          // t1/den = 8*(lo/den) - 8

// ws layout (bytes); ws_size ~268MB confirmed by harness poison fills
#define WS_FEATS 0           // float[2560]
#define WS_M     10240       // float[480]
#define WS_B2    12160       // float[20]
#define WS_PD    16384       // u32 [640*2000]  (5.12 MB)
#define WS_PP    5259264     // u64 [640*2000]  (10.24 MB)

// ---- gat_slice: 640 blocks (s=b/320, g=b%320) x 512 thr; round-6 edge loop on a half-window ----

__global__ __launch_bounds__(512) void gat_slice(
    const float* __restrict__ x, const float* __restrict__ edge_w,
    const int* __restrict__ src, const int* __restrict__ dst,
    const float* __restrict__ W_node, const float* __restrict__ W_edge,
    const float* __restrict__ attn_l, const float* __restrict__ attn_e,
    const float* __restrict__ attn_r,
    unsigned* __restrict__ pd, unsigned long long* __restrict__ pp)
{
    __shared__ float              xs[N_NODES];     // 8 KB
    __shared__ unsigned           aden[N_NODES];   // 8 KB
    __shared__ unsigned long long apk[N_NODES];    // 16 KB

    const int b   = blockIdx.x;
    const int s   = b / NG;
    const int g   = b % NG;
    const int tid = threadIdx.x;

    // rank-1 projections collapse to 3 scalar coefficients
    float cl = 0.f, ce = 0.f, cr = 0.f;
#pragma unroll
    for (int k = 0; k < OUTF; ++k) {
        cl += W_node[k] * attn_l[k];
        cr += W_node[k] * attn_r[k];
        ce += W_edge[k] * attn_e[k];
    }

    if (tid < N_NODES / 4)
        ((float4*)xs)[tid] = ((const float4*)(x + (size_t)g * N_NODES))[tid];
    for (int i = tid; i < N_NODES; i += 512) { aden[i] = 0u; apk[i] = 0ull; }
    __syncthreads();

    // edge pass over this slice's window: coalesced vec4, native int LDS atomics
    const int4*   src4 = (const int4*)src + (size_t)s * EV4;
    const int4*   dst4 = (const int4*)dst + (size_t)s * EV4;
    const float4* wg4  = (const float4*)(edge_w + (size_t)g * N_EDGES) + (size_t)s * EV4;
#pragma unroll
    for (int k = 0; k < (EV4 + 511) / 512; ++k) {
        const int c = tid + k * 512;
        if (c < EV4) {
            const int4   sv = src4[c];
            const int4   dv = dst4[c];
            const float4 wv = wg4[c];
#pragma unroll
            for (int j = 0; j < 4; ++j) {
                const int   sn = (&sv.x)[j];
                const int   dn = (&dv.x)[j];
                const float w  = (&wv.x)[j];
                const float xsv = xs[sn];
                float ev = cl * xsv + ce * w + cr * xs[dn];
                ev = fmaxf(ev, 0.2f * ev);          // leaky_relu
                const float num = __expf(ev);       // max-shift dropped: ratio-invariant
                const unsigned deni = __float2uint_rn(num * SC_DEN);
                const unsigned t1i  = __float2uint_rn(num * (xsv + XBIAS) * SC_T1);
                const unsigned t2i  = __float2uint_rn(num * w * SC_T2);
                atomicAdd(&aden[dn], deni);
                atomicAdd(&apk[dn], ((unsigned long long)t2i << 32) | (unsigned long long)t1i);
            }
        }
    }
    __syncthreads();

    // dump raw per-node partials (coalesced)
    for (int n = tid; n < N_NODES; n += 512) {
        pd[(size_t)b * N_NODES + n] = aden[n];
        pp[(size_t)b * N_NODES + n] = apk[n];
    }
}

// ---- combine: 321 blocks x 512 thr; block 320 = fused fcc@fc prep ----
// True per-node totals fit 32b, so u64 partial adds never carry lo->hi.

__global__ __launch_bounds__(512) void combine_kernel(
    const unsigned* __restrict__ pd, const unsigned long long* __restrict__ pp,
    const float* __restrict__ W_node, const float* __restrict__ W_edge,
    const float* __restrict__ gat_b,
    const float* __restrict__ fc_w, const float* __restrict__ fc_b,
    const float* __restrict__ fcc_w, const float* __restrict__ fcc_b,
    float* __restrict__ feats, float* __restrict__ Mw, float* __restrict__ b2w)
{
    __shared__ double wr1[8], wr2[8];
    const int tid = threadIdx.x;

    if (blockIdx.x == NG) {   // prep: M = fcc_w @ fc_w ; b2 = fcc_b + fcc_w @ fc_b
        if (tid < FCC_OUTD * HID) {
            const int j = tid / HID, h = tid % HID;
            float acc = 0.f;
#pragma unroll 4
            for (int m = 0; m < FC_OUTD; ++m)
                acc += fcc_w[j * FC_OUTD + m] * fc_w[m * HID + h];
            Mw[tid] = acc;
        } else if (tid < FCC_OUTD * HID + FCC_OUTD) {
            const int j = tid - FCC_OUTD * HID;
            float acc = fcc_b[j];
#pragma unroll 4
            for (int m = 0; m < FC_OUTD; ++m)
                acc += fcc_w[j * FC_OUTD + m] * fc_b[m];
            b2w[j] = acc;
        }
        return;
    }

    const int g = blockIdx.x;
    double s1 = 0.0, s2 = 0.0;
    for (int n = tid; n < N_NODES; n += 512) {
        const unsigned den = pd[(size_t)g * N_NODES + n] +
                             pd[(size_t)(NG + g) * N_NODES + n];
        if (den) {
            const unsigned long long pk = pp[(size_t)g * N_NODES + n] +
                                          pp[(size_t)(NG + g) * N_NODES + n];
            const double inv = 1.0 / (double)den;
            s1 += 8.0 * (double)(unsigned)(pk & 0xffffffffull) * inv - 8.0;
            s2 += (double)(unsigned)(pk >> 32) * inv;
        }
    }
#pragma unroll
    for (int off = 32; off > 0; off >>= 1) {
        s1 += __shfl_down(s1, off, 64);
        s2 += __shfl_down(s2, off, 64);
    }
    const int wave = tid >> 6, lane = tid & 63;
    if (lane == 0) { wr1[wave] = s1; wr2[wave] = s2; }
    __syncthreads();
    if (tid == 0) {
        double a = 0.0, c = 0.0;
#pragma unroll
        for (int w = 0; w < 8; ++w) { a += wr1[w]; c += wr2[w]; }
#pragma unroll
        for (int k = 0; k < OUTF; ++k)
            feats[g * OUTF + k] = gat_b[k] +
                (float)((a * (double)W_node[k] + c * (double)W_edge[k]) / (double)N_NODES);
    }
}

// ---------------- head: 16 blocks (one per batch): LSTM + precomputed-M ----------------

__device__ __forceinline__ float fast_sigmoid(float v) { return 1.f / (1.f + __expf(-v)); }
__device__ __forceinline__ float fast_tanh(float v) {
    const float t = __expf(2.f * v);
    return (t - 1.f) / (t + 1.f);
}

__global__ __launch_bounds__(128) void lstm_head(
    const float* __restrict__ feats, const float* __restrict__ Mw,
    const float* __restrict__ b2w,
    const float* __restrict__ w_ih, const float* __restrict__ w_hh,
    const float* __restrict__ b_ih, const float* __restrict__ b_hh,
    float* __restrict__ out)
{
    __shared__ float s_M[FCC_OUTD * HID];
    __shared__ float s_b2[FCC_OUTD];
    __shared__ float s_xt[TT * OUTF];
    __shared__ float s_bias[96];
    __shared__ float s_xg[TT * 96];
    __shared__ float s_g[96];
    __shared__ float s_h[HID], s_c[HID];
    __shared__ float s_hs[TT * HID];

    const int b = blockIdx.x, tid = threadIdx.x;
    for (int i = tid; i < FCC_OUTD * HID; i += 128) s_M[i] = Mw[i];
    if (tid < FCC_OUTD) s_b2[tid] = b2w[tid];
    for (int i = tid; i < TT * OUTF; i += 128) s_xt[i] = feats[b * TT * OUTF + i];
    if (tid < 96) s_bias[tid] = b_ih[tid] + b_hh[tid];
    if (tid < HID) { s_h[tid] = 0.f; s_c[tid] = 0.f; }
    float rw_hh[HID];
    if (tid < 96) {
#pragma unroll
        for (int k = 0; k < HID; ++k) rw_hh[k] = w_hh[tid * HID + k];
    }
    __syncthreads();
    for (int u = tid; u < TT * 96; u += 128) {
        const int t = u / 96, j = u % 96;
        float acc = s_bias[j];
        const float* xt = &s_xt[t * OUTF];
#pragma unroll
        for (int k = 0; k < OUTF; ++k) acc += xt[k] * w_ih[j * OUTF + k];
        s_xg[u] = acc;
    }
    __syncthreads();
    for (int t = 0; t < TT; ++t) {
        if (tid < 96) {
            float acc = s_xg[t * 96 + tid];
#pragma unroll
            for (int k = 0; k < HID; ++k) acc += s_h[k] * rw_hh[k];
            s_g[tid] = acc;
        }
        __syncthreads();
        if (tid < HID) {
            const float i_ = fast_sigmoid(s_g[tid]);
            const float f_ = fast_sigmoid(s_g[24 + tid]);
            const float g_ = fast_tanh(s_g[48 + tid]);
            const float o_ = fast_sigmoid(s_g[72 + tid]);
            const float c = f_ * s_c[tid] + i_ * g_;
            s_c[tid] = c;
            const float hv = o_ * fast_tanh(c);
            s_h[tid] = hv;
            s_hs[t * HID + tid] = hv;
        }
        __syncthreads();
    }
    for (int u = tid; u < TT * FCC_OUTD; u += 128) {
        const int t = u / FCC_OUTD, j = u % FCC_OUTD;
        float acc = s_b2[j];
        const float* hr = &s_hs[t * HID];
#pragma unroll
        for (int h = 0; h < HID; ++h) acc += hr[h] * s_M[j * HID + h];
        out[(b * TT + t) * FCC_OUTD + j] = acc;
    }
}

extern "C" void kernel_launch(void* const* d_in, const int* in_sizes, int n_in,
                              void* d_out, int out_size, void* d_ws, size_t ws_size,
                              hipStream_t stream) {
    const float* x      = (const float*)d_in[0];
    const float* edge_w = (const float*)d_in[1];
    const int*   src    = (const int*)d_in[2];
    const int*   dst    = (const int*)d_in[3];
    const float* W_node = (const float*)d_in[4];
    const float* W_edge = (const float*)d_in[5];
    const float* attn_l = (const float*)d_in[6];
    const float* attn_e = (const float*)d_in[7];
    const float* attn_r = (const float*)d_in[8];
    const float* gat_b  = (const float*)d_in[9];
    const float* w_ih   = (const float*)d_in[10];
    const float* w_hh   = (const float*)d_in[11];
    const float* b_ih   = (const float*)d_in[12];
    const float* b_hh   = (const float*)d_in[13];
    const float* fc_w   = (const float*)d_in[14];
    const float* fc_b   = (const float*)d_in[15];
    const float* fcc_w  = (const float*)d_in[16];
    const float* fcc_b  = (const float*)d_in[17];

    char* ws = (char*)d_ws;
    float*              feats = (float*)(ws + WS_FEATS);
    float*              Mw    = (float*)(ws + WS_M);
    float*              b2w   = (float*)(ws + WS_B2);
    unsigned*           pd    = (unsigned*)(ws + WS_PD);
    unsigned long long* pp    = (unsigned long long*)(ws + WS_PP);
    float*              out   = (float*)d_out;

    gat_slice<<<NSLICE * NG, 512, 0, stream>>>(x, edge_w, src, dst,
                                               W_node, W_edge, attn_l, attn_e, attn_r,
                                               pd, pp);
    combine_kernel<<<NG + 1, 512, 0, stream>>>(pd, pp, W_node, W_edge, gat_b,
                                               fc_w, fc_b, fcc_w, fcc_b,
                                               feats, Mw, b2w);
    lstm_head<<<BB, 128, 0, stream>>>(feats, Mw, b2w, w_ih, w_hh, b_ih, b_hh, out);
}